// Round 15
// baseline (435.748 us; speedup 1.0000x reference)
//
#include <hip/hip_runtime.h>
#include <hip/hip_bf16.h>

// LlamaAttention_49392123904401 — per-token head-mixing "attention".
// fp32 inputs (runtime-detected), bf16 MFMA compute, output in input dtype.
// Round 15: fuse the X fp32->bf16 conversion INTO qkv's A-staging (reg-stage
// + cvt + ds_write, T14 issue-early/write-late), eliminating the Xb buffer
// and ~200MB of convert traffic. convert_all now does weights only (24MB).
// GEMM schedules unchanged from r14 (core8 qkv / core4 out, best measured).

typedef short bf16x8 __attribute__((ext_vector_type(8)));   // 8 bf16 = 4 VGPRs
typedef float f32x4  __attribute__((ext_vector_type(4)));

__device__ __forceinline__ float bf2f(short u) {
    union { unsigned int ui; float f; } cv;
    cv.ui = ((unsigned int)(unsigned short)u) << 16;
    return cv.f;
}
__device__ __forceinline__ short f2bf(float f) {
    __hip_bfloat16 h = __float2bfloat16(f);
    return *reinterpret_cast<short*>(&h);
}

// async global->LDS, 16B per lane. LDS dest = wave-uniform base + lane*16.
__device__ __forceinline__ void gload_lds16(const void* g, void* lds) {
    const unsigned __attribute__((address_space(1)))* gp =
        reinterpret_cast<const unsigned __attribute__((address_space(1)))*>((unsigned long long)g);
    unsigned __attribute__((address_space(3)))* lp =
        reinterpret_cast<unsigned __attribute__((address_space(3)))*>(
            (unsigned int)(unsigned long long)lds);
    __builtin_amdgcn_global_load_lds(gp, lp, 16, 0, 0);
}

// ---------------------------------------------------------------------------
// dtype sniffer (flag: 1 = fp32 inputs, 0 = bf16 inputs).
// ---------------------------------------------------------------------------
__global__ void detect_dtype(const unsigned* __restrict__ x, int* __restrict__ flag) {
    __shared__ int cnt;
    if (threadIdx.x == 0) cnt = 0;
    __syncthreads();
    int c = 0;
    for (int i = threadIdx.x; i < 4096; i += 256) {
        const unsigned u = x[(long)i * 4001 + 3];
        const unsigned b = (u >> 7) & 0xFF;
        c += (b >= 0x70 && b <= 0x87) ? 1 : 0;
    }
    atomicAdd(&cnt, c);
    __syncthreads();
    if (threadIdx.x == 0) *flag = (cnt > 2048) ? 0 : 1;   // HIGH => bf16
}

// ---------------------------------------------------------------------------
// Weights-only conversion into contiguous [Wq|Wk|Wv|Wo] bf16 region.
// ---------------------------------------------------------------------------
__global__ void convert_all(const void* __restrict__ X,
                            const void* __restrict__ W0, const void* __restrict__ W1,
                            const void* __restrict__ W2, const void* __restrict__ W3,
                            short* __restrict__ dst, long total,
                            const int* __restrict__ flag) {
    constexpr long WELEM = 1024 * 1024;
    const int f = *flag;
    const long step = (long)gridDim.x * blockDim.x * 8;
    for (long i = ((long)blockIdx.x * blockDim.x + threadIdx.x) * 8; i < total; i += step) {
        const void* src;
        long off;
        if (i < 4 * WELEM) {
            const int w = (int)(i >> 20);
            src = (w == 0) ? W0 : (w == 1) ? W1 : (w == 2) ? W2 : W3;
            off = i & (WELEM - 1);
        } else {
            src = X;
            off = i - 4 * WELEM;
        }
        if (f) {
            const float* s = (const float*)src + off;
            const f32x4 a = *(const f32x4*)s;
            const f32x4 b = *(const f32x4*)(s + 4);
            bf16x8 o;
            o[0] = f2bf(a[0]); o[1] = f2bf(a[1]); o[2] = f2bf(a[2]); o[3] = f2bf(a[3]);
            o[4] = f2bf(b[0]); o[5] = f2bf(b[1]); o[6] = f2bf(b[2]); o[7] = f2bf(b[3]);
            *(bf16x8*)(dst + i) = o;
        } else {
            *(bf16x8*)(dst + i) = *(const bf16x8*)((const short*)src + off);
        }
    }
}

// ---------------------------------------------------------------------------
// CORE-8 (qkv): 512 thr = 8 waves (2Mx4N), wave 128x64. r6 schedule.
// A-source is fp32 X (af32=1): reg-staged fp32->bf16->ds_write, split so
// units 0-1 load@ph0/write@ph1-start and units 2-3 load@ph1/write@ph1-end
// (HBM latency hidden under a phase of MFMA+reads). af32=0: gload_lds direct.
// B (weights) always bf16 via gload_lds. XOR k-chunk swizzle throughout.
// ---------------------------------------------------------------------------
__device__ __forceinline__ void gemm256_core8(const void* __restrict__ Asrc,
                                              const short* __restrict__ W,
                                              void* __restrict__ C,
                                              const int* out_f32,
                                              const int* a_f32,
                                              long arow_off,
                                              long m0, int n0, short* lds) {
    constexpr int K = 1024, N = 1024;
    const int tid  = threadIdx.x;
    const int lane = tid & 63;
    const int wid  = tid >> 6;
    const int wm = wid >> 2, wn = wid & 3;
    const int af32 = a_f32 ? *a_f32 : 0;
    const short* Ab = (const short*)Asrc;
    const float* Af = (const float*)Asrc;

    short* A0 = lds;              // 16384 shorts = 32KB each
    short* B0 = lds + 16384;
    short* A1 = lds + 32768;
    short* B1 = lds + 49152;

    const int srl = tid >> 3;                    // 0..63
    const int kcs = (tid & 7) ^ (srl & 7);       // logical k-chunk (swizzle inv)
    int aoff[4], boff[4];
    #pragma unroll
    for (int i = 0; i < 4; ++i) {
        const int row = i * 64 + srl;
        aoff[i] = (int)((arow_off + m0 + row) * K + kcs * 8);
        boff[i] = (n0 + row) * K + kcs * 8;
    }
    const int ldsw = wid * 512;                  // wave's lane0 slot (shorts)
    const int tslot = tid << 3;                  // this thread's slot (shorts)

    f32x4 acc[8][4] = {};

    // prologue: tile 0. A via cvt path (one-time stall ok) or gload_lds.
    if (af32) {
        #pragma unroll
        for (int u = 0; u < 4; ++u) {
            const float* s = Af + aoff[u];
            const f32x4 lo = *(const f32x4*)s;
            const f32x4 hi = *(const f32x4*)(s + 4);
            bf16x8 o;
            o[0] = f2bf(lo[0]); o[1] = f2bf(lo[1]); o[2] = f2bf(lo[2]); o[3] = f2bf(lo[3]);
            o[4] = f2bf(hi[0]); o[5] = f2bf(hi[1]); o[6] = f2bf(hi[2]); o[7] = f2bf(hi[3]);
            *(bf16x8*)(A0 + u * 4096 + tslot) = o;
        }
    } else {
        #pragma unroll
        for (int u = 0; u < 4; ++u)
            gload_lds16(Ab + aoff[u], A0 + u * 4096 + ldsw);
    }
    #pragma unroll
    for (int u = 0; u < 4; ++u)
        gload_lds16(W + boff[u], B0 + u * 4096 + ldsw);
    asm volatile("s_waitcnt vmcnt(0) lgkmcnt(0)" ::: "memory");
    __builtin_amdgcn_s_barrier();

    for (int t = 0; t < 16; ++t) {
        const int cur = t & 1;
        const short* rA = cur ? A1 : A0;
        const short* rB = cur ? B1 : B0;
        short* sA = cur ? A0 : A1;
        short* sB = cur ? B0 : B1;
        const int kadd = (t + 1) * 64;
        const bool more = (t < 15);

        // ================= ph0 (ks=0) =================
        f32x4 a0lo, a0hi, a1lo, a1hi;
        if (more && af32) {                       // issue units 0,1 early
            const float* s0 = Af + aoff[0] + kadd;
            a0lo = *(const f32x4*)s0; a0hi = *(const f32x4*)(s0 + 4);
            const float* s1 = Af + aoff[1] + kadd;
            a1lo = *(const f32x4*)s1; a1hi = *(const f32x4*)(s1 + 4);
        }
        {
            const int kx8 = (((lane >> 4)) ^ (lane & 7)) * 8;
            bf16x8 af[8], bfr[4];
            #pragma unroll
            for (int m = 0; m < 8; ++m)
                af[m] = *(const bf16x8*)(rA + ((wm * 128 + m * 16 + (lane & 15)) * 64) + kx8);
            #pragma unroll
            for (int n = 0; n < 4; ++n)
                bfr[n] = *(const bf16x8*)(rB + ((wn * 64 + n * 16 + (lane & 15)) * 64) + kx8);
            __builtin_amdgcn_sched_barrier(0);
            __builtin_amdgcn_s_barrier();              // bar_a0
            __builtin_amdgcn_sched_barrier(0);
            if (more && !af32) {
                #pragma unroll
                for (int u = 0; u < 4; ++u)
                    gload_lds16(Ab + aoff[u] + kadd, sA + u * 4096 + ldsw);
            }
            asm volatile("s_waitcnt lgkmcnt(0)" ::: "memory");
            __builtin_amdgcn_sched_barrier(0);
            __builtin_amdgcn_s_setprio(1);
            #pragma unroll
            for (int m = 0; m < 8; ++m)
                #pragma unroll
                for (int n = 0; n < 4; ++n)
                    acc[m][n] = __builtin_amdgcn_mfma_f32_16x16x32_bf16(
                                    af[m], bfr[n], acc[m][n], 0, 0, 0);
            __builtin_amdgcn_s_setprio(0);
            __builtin_amdgcn_sched_barrier(0);
        }

        // ================= ph1 (ks=1) =================
        {
            const int kx8 = ((4 + (lane >> 4)) ^ (lane & 7)) * 8;
            bf16x8 af[8], bfr[4];
            #pragma unroll
            for (int m = 0; m < 8; ++m)
                af[m] = *(const bf16x8*)(rA + ((wm * 128 + m * 16 + (lane & 15)) * 64) + kx8);
            #pragma unroll
            for (int n = 0; n < 4; ++n)
                bfr[n] = *(const bf16x8*)(rB + ((wn * 64 + n * 16 + (lane & 15)) * 64) + kx8);
            __builtin_amdgcn_sched_barrier(0);
            __builtin_amdgcn_s_barrier();              // bar_a1
            __builtin_amdgcn_sched_barrier(0);
            f32x4 a2lo, a2hi, a3lo, a3hi;
            if (more && af32) {
                // write units 0,1 (loads issued a full phase ago — covered)
                {
                    bf16x8 o;
                    o[0] = f2bf(a0lo[0]); o[1] = f2bf(a0lo[1]); o[2] = f2bf(a0lo[2]); o[3] = f2bf(a0lo[3]);
                    o[4] = f2bf(a0hi[0]); o[5] = f2bf(a0hi[1]); o[6] = f2bf(a0hi[2]); o[7] = f2bf(a0hi[3]);
                    *(bf16x8*)(sA + 0 * 4096 + tslot) = o;
                }
                {
                    bf16x8 o;
                    o[0] = f2bf(a1lo[0]); o[1] = f2bf(a1lo[1]); o[2] = f2bf(a1lo[2]); o[3] = f2bf(a1lo[3]);
                    o[4] = f2bf(a1hi[0]); o[5] = f2bf(a1hi[1]); o[6] = f2bf(a1hi[2]); o[7] = f2bf(a1hi[3]);
                    *(bf16x8*)(sA + 1 * 4096 + tslot) = o;
                }
                // issue units 2,3 (written after MFMA below)
                const float* s2 = Af + aoff[2] + kadd;
                a2lo = *(const f32x4*)s2; a2hi = *(const f32x4*)(s2 + 4);
                const float* s3 = Af + aoff[3] + kadd;
                a3lo = *(const f32x4*)s3; a3hi = *(const f32x4*)(s3 + 4);
            }
            if (more) {
                #pragma unroll
                for (int u = 0; u < 4; ++u)
                    gload_lds16(W + boff[u] + kadd, sB + u * 4096 + ldsw);
            }
            asm volatile("s_waitcnt lgkmcnt(0)" ::: "memory");
            __builtin_amdgcn_sched_barrier(0);
            __builtin_amdgcn_s_setprio(1);
            #pragma unroll
            for (int m = 0; m < 8; ++m)
                #pragma unroll
                for (int n = 0; n < 4; ++n)
                    acc[m][n] = __builtin_amdgcn_mfma_f32_16x16x32_bf16(
                                    af[m], bfr[n], acc[m][n], 0, 0, 0);
            __builtin_amdgcn_s_setprio(0);
            __builtin_amdgcn_sched_barrier(0);
            if (more && af32) {
                {
                    bf16x8 o;
                    o[0] = f2bf(a2lo[0]); o[1] = f2bf(a2lo[1]); o[2] = f2bf(a2lo[2]); o[3] = f2bf(a2lo[3]);
                    o[4] = f2bf(a2hi[0]); o[5] = f2bf(a2hi[1]); o[6] = f2bf(a2hi[2]); o[7] = f2bf(a2hi[3]);
                    *(bf16x8*)(sA + 2 * 4096 + tslot) = o;
                }
                {
                    bf16x8 o;
                    o[0] = f2bf(a3lo[0]); o[1] = f2bf(a3lo[1]); o[2] = f2bf(a3lo[2]); o[3] = f2bf(a3lo[3]);
                    o[4] = f2bf(a3hi[0]); o[5] = f2bf(a3hi[1]); o[6] = f2bf(a3hi[2]); o[7] = f2bf(a3hi[3]);
                    *(bf16x8*)(sA + 3 * 4096 + tslot) = o;
                }
                asm volatile("s_waitcnt lgkmcnt(0)" ::: "memory");  // writes drained
                __builtin_amdgcn_sched_barrier(0);
            }
            if (more) {
                asm volatile("s_waitcnt vmcnt(0)" ::: "memory");    // B staged
                __builtin_amdgcn_s_barrier();          // bar_b
            }
        }
    }

    // epilogue: C/D layout col=lane&15, row=(lane>>4)*4+r
    const int f = out_f32 ? *out_f32 : 0;
    #pragma unroll
    for (int mf = 0; mf < 8; ++mf) {
        #pragma unroll
        for (int nf = 0; nf < 4; ++nf) {
            const int  col   = n0 + wn * 64 + nf * 16 + (lane & 15);
            const long rbase = m0 + wm * 128 + mf * 16 + (lane >> 4) * 4;
            if (f) {
                float* Cf = (float*)C;
                #pragma unroll
                for (int r = 0; r < 4; ++r)
                    Cf[(rbase + r) * N + col] = acc[mf][nf][r];
            } else {
                short* Cs = (short*)C;
                #pragma unroll
                for (int r = 0; r < 4; ++r)
                    Cs[(rbase + r) * N + col] = f2bf(acc[mf][nf][r]);
            }
        }
    }
}

// ---------------------------------------------------------------------------
// CORE-4 (out): 256 thr = 4 waves (2Mx2N), wave tile 128x128 (r13, unchanged).
// ---------------------------------------------------------------------------
__device__ __forceinline__ void gemm256_core4(const short* __restrict__ A,
                                              const short* __restrict__ W,
                                              void* __restrict__ C,
                                              const int* flag_fp32,
                                              long m0, int n0, short* lds) {
    constexpr int K = 1024, N = 1024;
    const int tid  = threadIdx.x;
    const int lane = tid & 63;
    const int wid  = tid >> 6;
    const int wm = wid >> 1, wn = wid & 1;

    short* A0 = lds;
    short* B0 = lds + 16384;
    short* A1 = lds + 32768;
    short* B1 = lds + 49152;

    const int srl = tid >> 3;                    // 0..31
    const int kcs = (tid & 7) ^ (srl & 7);
    int aoff[8], boff[8];
    #pragma unroll
    for (int i = 0; i < 8; ++i) {
        const int row = i * 32 + srl;
        aoff[i] = (int)((m0 + row) * K + kcs * 8);
        boff[i] = (n0 + row) * K + kcs * 8;
    }
    const int ldsw = wid * 512;

    f32x4 acc[8][8] = {};

    #pragma unroll
    for (int i = 0; i < 8; ++i) gload_lds16(A + aoff[i], A0 + i * 2048 + ldsw);
    #pragma unroll
    for (int i = 0; i < 8; ++i) gload_lds16(W + boff[i], B0 + i * 2048 + ldsw);
    asm volatile("s_waitcnt vmcnt(0)" ::: "memory");
    __builtin_amdgcn_s_barrier();

    const int arow = wm * 128 + (lane & 15);
    const int brow = wn * 128 + (lane & 15);

    for (int t = 0; t < 16; ++t) {
        const int cur = t & 1;
        const short* rA = cur ? A1 : A0;
        const short* rB = cur ? B1 : B0;
        short* sA = cur ? A0 : A1;
        short* sB = cur ? B0 : B1;
        const int kadd = (t + 1) * 64;
        const bool more = (t < 15);

        #pragma unroll
        for (int ks = 0; ks < 2; ++ks) {
            const int kx8 = ((ks * 4 + (lane >> 4)) ^ (lane & 7)) * 8;
            bf16x8 af[8], bfr[8];
            #pragma unroll
            for (int m = 0; m < 8; ++m)
                af[m] = *(const bf16x8*)(rA + ((arow + m * 16) * 64) + kx8);
            #pragma unroll
            for (int n = 0; n < 8; ++n)
                bfr[n] = *(const bf16x8*)(rB + ((brow + n * 16) * 64) + kx8);
            __builtin_amdgcn_sched_barrier(0);
            __builtin_amdgcn_s_barrier();
            __builtin_amdgcn_sched_barrier(0);
            if (more) {
                if (ks == 0) {
                    #pragma unroll
                    for (int i = 0; i < 8; ++i)
                        gload_lds16(A + aoff[i] + kadd, sA + i * 2048 + ldsw);
                } else {
                    #pragma unroll
                    for (int i = 0; i < 8; ++i)
                        gload_lds16(W + boff[i] + kadd, sB + i * 2048 + ldsw);
                }
            }
            asm volatile("s_waitcnt lgkmcnt(0)" ::: "memory");
            __builtin_amdgcn_sched_barrier(0);
            __builtin_amdgcn_s_setprio(1);
            #pragma unroll
            for (int m = 0; m < 8; ++m)
                #pragma unroll
                for (int n = 0; n < 8; ++n)
                    acc[m][n] = __builtin_amdgcn_mfma_f32_16x16x32_bf16(
                                    af[m], bfr[n], acc[m][n], 0, 0, 0);
            __builtin_amdgcn_s_setprio(0);
            __builtin_amdgcn_sched_barrier(0);
            if (ks == 1) {
                asm volatile("s_waitcnt vmcnt(0)" ::: "memory");
                __builtin_amdgcn_s_barrier();
            }
        }
    }

    const int f = flag_fp32 ? *flag_fp32 : 0;
    #pragma unroll
    for (int mf = 0; mf < 8; ++mf) {
        #pragma unroll
        for (int nf = 0; nf < 8; ++nf) {
            const int  col   = n0 + wn * 128 + nf * 16 + (lane & 15);
            const long rbase = m0 + wm * 128 + mf * 16 + (lane >> 4) * 4;
            if (f) {
                float* Cf = (float*)C;
                #pragma unroll
                for (int r = 0; r < 4; ++r)
                    Cf[(rbase + r) * N + col] = acc[mf][nf][r];
            } else {
                short* Cs = (short*)C;
                #pragma unroll
                for (int r = 0; r < 4; ++r)
                    Cs[(rbase + r) * N + col] = f2bf(acc[mf][nf][r]);
            }
        }
    }
}

// QKV (core-8): nwg = (Mc/256)*12, XCD-bijective remap, A-panel grouped.
// A = original X (dtype via flag), weights pre-converted bf16.
__global__ __launch_bounds__(512, 2) void gemm_qkv256(const void* __restrict__ X,
                                                      const short* __restrict__ W0,
                                                      const short* __restrict__ W1,
                                                      const short* __restrict__ W2,
                                                      short* __restrict__ C0,
                                                      short* __restrict__ C1,
                                                      short* __restrict__ C2,
                                                      const int* __restrict__ flag,
                                                      long arow_off) {
    __shared__ __align__(16) short lds[65536];            // 128 KiB
    const int nwg = gridDim.x;
    const int q8  = nwg >> 3;
    const int d   = blockIdx.x;
    const int lin = (d & 7) * q8 + (d >> 3);
    const int x   = lin / 12;
    const int r   = lin - x * 12;
    const int yy  = r / 3;
    const int z   = r - yy * 3;
    const short* W = (z == 0) ? W0 : (z == 1) ? W1 : W2;
    short*       C = (z == 0) ? C0 : (z == 1) ? C1 : C2;
    gemm256_core8(X, W, C, nullptr, flag, arow_off, (long)x * 256, yy * 256, lds);
}

// OUT (core-4): nwg = (Mc/256)*4. A pre-rebased by caller (A - moff*K).
__global__ __launch_bounds__(256, 1) void gemm_out256(const short* __restrict__ A,
                                                      const short* __restrict__ W,
                                                      void* __restrict__ C,
                                                      long moff,
                                                      const int* __restrict__ flag) {
    __shared__ __align__(16) short lds[65536];
    const int nwg = gridDim.x;
    const int q8  = nwg >> 3;
    const int d   = blockIdx.x;
    const int lin = (d & 7) * q8 + (d >> 3);
    const int x   = lin >> 2;
    const int yy  = lin & 3;
    gemm256_core4(A, W, C, flag, moff + (long)x * 256, yy * 256, lds);
}

// ---------------------------------------------------------------------------
// Per-token head mixing: scores = Q[16,64]@K[16,64]^T/8, softmax, Z = P@V.
// One wave per token, 4 tokens per 256-thread block.
// ---------------------------------------------------------------------------
__global__ __launch_bounds__(256) void attn_mix(const short* __restrict__ Q,
                                                const short* __restrict__ K,
                                                const short* __restrict__ V,
                                                short* __restrict__ Z) {
    constexpr int RS = 72;
    __shared__ short sq[4][16 * RS];
    __shared__ short sk[4][16 * RS];
    __shared__ short sv[4][16 * RS];
    __shared__ float sp[4][256];

    const int  tid  = threadIdx.x;
    const int  lane = tid & 63;
    const int  w    = tid >> 6;
    const long tok  = (long)blockIdx.x * 4 + w;

    const short* qg = Q + tok * 1024;
    const short* kg = K + tok * 1024;
    const short* vg = V + tok * 1024;

    #pragma unroll
    for (int it = 0; it < 2; ++it) {
        const int c   = lane + 64 * it;
        const int row = c >> 3;
        const int cc  = (c & 7) * 8;
        *(bf16x8*)&sq[w][row * RS + cc] = *(const bf16x8*)(qg + c * 8);
        *(bf16x8*)&sk[w][row * RS + cc] = *(const bf16x8*)(kg + c * 8);
        *(bf16x8*)&sv[w][row * RS + cc] = *(const bf16x8*)(vg + c * 8);
    }
    __syncthreads();

    const int h  = lane >> 2;
    const int t0 = (lane & 3) * 4;
    float sc[4] = {0.f, 0.f, 0.f, 0.f};
    for (int d = 0; d < 64; ++d) {
        const float qv = bf2f(sq[w][h * RS + d]);
        #pragma unroll
        for (int j = 0; j < 4; ++j)
            sc[j] += qv * bf2f(sk[w][(t0 + j) * RS + d]);
    }
    #pragma unroll
    for (int j = 0; j < 4; ++j) sc[j] *= 0.125f;

    float mx = fmaxf(fmaxf(sc[0], sc[1]), fmaxf(sc[2], sc[3]));
    mx = fmaxf(mx, __shfl_xor(mx, 1));
    mx = fmaxf(mx, __shfl_xor(mx, 2));
    float ex[4], s = 0.f;
    #pragma unroll
    for (int j = 0; j < 4; ++j) { ex[j] = __expf(sc[j] - mx); s += ex[j]; }
    s += __shfl_xor(s, 1);
    s += __shfl_xor(s, 2);
    const float inv = 1.f / s;
    #pragma unroll
    for (int j = 0; j < 4; ++j) sp[w][h * 16 + t0 + j] = ex[j] * inv;
    __syncthreads();

    const int dbase = (lane & 3) * 16;
    float o[16] = {};
    for (int t = 0; t < 16; ++t) {
        const float p = sp[w][h * 16 + t];
        const bf16x8 v0 = *(const bf16x8*)&sv[w][t * RS + dbase];
        const bf16x8 v1 = *(const bf16x8*)&sv[w][t * RS + dbase + 8];
        #pragma unroll
        for (int e = 0; e < 8; ++e) {
            o[e]     += p * bf2f(v0[e]);
            o[e + 8] += p * bf2f(v1[e]);
        }
    }
    bf16x8 ov0, ov1;
    #pragma unroll
    for (int e = 0; e < 8; ++e) { ov0[e] = f2bf(o[e]); ov1[e] = f2bf(o[e + 8]); }
    *(bf16x8*)(Z + tok * 1024 + lane * 16)     = ov0;
    *(bf16x8*)(Z + tok * 1024 + lane * 16 + 8) = ov1;
}

// ---------------------------------------------------------------------------
extern "C" void kernel_launch(void* const* d_in, const int* in_sizes, int n_in,
                              void* d_out, int out_size, void* d_ws, size_t ws_size,
                              hipStream_t stream) {
    const void* X = d_in[0];                   // [32768,1024] fp32 (detected)

    const long TOT = 32768;
    constexpr long WELEM = 1024 * 1024;

    char* ws   = (char*)d_ws;
    int*  flag = (int*)ws;
    short* Wqb = (short*)(ws + 256);           // [Wq|Wk|Wv|Wo] contiguous bf16
    short* Wkb = Wqb + WELEM;
    short* Wvb = Wkb + WELEM;
    short* Wob = Wvb + WELEM;
    short* dyn = Wob + WELEM;

    const size_t fixed = 256 + 4 * WELEM * 2;  // ≈8.4 MB
    long chunk = 256;
    const long tiers[4] = {32768, 8192, 2048, 512};
    for (int i = 0; i < 4; ++i)
        if (fixed + (size_t)8 * tiers[i] * 1024 <= ws_size) { chunk = tiers[i]; break; }

    short* Qb = dyn;                 // chunk*1024 bf16 each
    short* Kb = Qb + chunk * 1024;
    short* Vb = Kb + chunk * 1024;
    short* Zb = Vb + chunk * 1024;

    detect_dtype<<<1, 256, 0, stream>>>((const unsigned*)X, flag);
    // weights only (X is consumed directly by qkv with fused conversion)
    convert_all<<<512, 256, 0, stream>>>(X, d_in[1], d_in[2], d_in[3], d_in[4],
                                         Wqb, 4 * WELEM, flag);

    for (long t0 = 0; t0 < TOT; t0 += chunk) {
        gemm_qkv256<<<dim3((chunk / 256) * 12), 512, 0, stream>>>(
            X, Wqb, Wkb, Wvb, Qb, Kb, Vb, flag, t0);
        attn_mix<<<dim3(chunk / 4), 256, 0, stream>>>(Qb, Kb, Vb, Zb);
        gemm_out256<<<dim3((chunk / 256) * 4), 256, 0, stream>>>(
            Zb - t0 * 1024, Wob, d_out, t0, flag);
    }
}

// Round 16
// 388.915 us; speedup vs baseline: 1.1204x; 1.1204x over previous
//
#include <hip/hip_runtime.h>
#include <hip/hip_bf16.h>

// LlamaAttention_49392123904401 — per-token head-mixing "attention".
// fp32 inputs (runtime-detected), bf16 MFMA compute, output in input dtype.
// Round 16: revert to r14 structure (best: core8 qkv 217us/42%, core4 out,
// Xb convert path) + fold dtype detection into consumers (per-block 64-sample
// ballot sniff — deterministic, identical across blocks). 4 launches:
// convert_all, gemm_qkv256, attn_mix, gemm_out256.

typedef short bf16x8 __attribute__((ext_vector_type(8)));   // 8 bf16 = 4 VGPRs
typedef float f32x4  __attribute__((ext_vector_type(4)));

__device__ __forceinline__ float bf2f(short u) {
    union { unsigned int ui; float f; } cv;
    cv.ui = ((unsigned int)(unsigned short)u) << 16;
    return cv.f;
}
__device__ __forceinline__ short f2bf(float f) {
    __hip_bfloat16 h = __float2bfloat16(f);
    return *reinterpret_cast<short*>(&h);
}

// async global->LDS, 16B per lane. LDS dest = wave-uniform base + lane*16.
__device__ __forceinline__ void gload_lds16(const void* g, void* lds) {
    const unsigned __attribute__((address_space(1)))* gp =
        reinterpret_cast<const unsigned __attribute__((address_space(1)))*>((unsigned long long)g);
    unsigned __attribute__((address_space(3)))* lp =
        reinterpret_cast<unsigned __attribute__((address_space(3)))*>(
            (unsigned int)(unsigned long long)lds);
    __builtin_amdgcn_global_load_lds(gp, lp, 16, 0, 0);
}

// ---------------------------------------------------------------------------
// Inline dtype sniff: 64 strided u32 samples of X; bits 14:7 = bf16 exponent
// of low element (in [0x70,0x87] w.p. ~1 for N(0,1) bf16) vs fp32 mantissa
// bits (~9%). Majority ballot over the wave. Deterministic & block-uniform.
// Returns 1 = fp32 inputs, 0 = bf16 inputs.
// ---------------------------------------------------------------------------
__device__ __forceinline__ int sniff_fp32(const unsigned* __restrict__ x) {
    const int l = (int)(threadIdx.x & 63);
    const unsigned u = x[(long)l * 262147 + 11];   // max idx 16.52M < 16.77M
    const unsigned b = (u >> 7) & 0xFF;
    const unsigned long long m = __ballot(b >= 0x70 && b <= 0x87);
    return (__popcll(m) > 32) ? 0 : 1;             // majority in-range => bf16
}

// ---------------------------------------------------------------------------
// ONE conversion pass over contiguous [Wq|Wk|Wv|Wo|X] bf16 region.
// ---------------------------------------------------------------------------
__global__ void convert_all(const void* __restrict__ X,
                            const void* __restrict__ W0, const void* __restrict__ W1,
                            const void* __restrict__ W2, const void* __restrict__ W3,
                            short* __restrict__ dst, long total) {
    constexpr long WELEM = 1024 * 1024;
    const int f = sniff_fp32((const unsigned*)X);
    const long step = (long)gridDim.x * blockDim.x * 8;
    for (long i = ((long)blockIdx.x * blockDim.x + threadIdx.x) * 8; i < total; i += step) {
        const void* src;
        long off;
        if (i < 4 * WELEM) {
            const int w = (int)(i >> 20);
            src = (w == 0) ? W0 : (w == 1) ? W1 : (w == 2) ? W2 : W3;
            off = i & (WELEM - 1);
        } else {
            src = X;
            off = i - 4 * WELEM;
        }
        if (f) {
            const float* s = (const float*)src + off;
            const f32x4 a = *(const f32x4*)s;
            const f32x4 b = *(const f32x4*)(s + 4);
            bf16x8 o;
            o[0] = f2bf(a[0]); o[1] = f2bf(a[1]); o[2] = f2bf(a[2]); o[3] = f2bf(a[3]);
            o[4] = f2bf(b[0]); o[5] = f2bf(b[1]); o[6] = f2bf(b[2]); o[7] = f2bf(b[3]);
            *(bf16x8*)(dst + i) = o;
        } else {
            *(bf16x8*)(dst + i) = *(const bf16x8*)((const short*)src + off);
        }
    }
}

// ---------------------------------------------------------------------------
// CORE-8 (qkv): 512 thr = 8 waves (2Mx4N), wave 128x64. r6 schedule.
// BK=64, 16 K-tiles, dbuf, 2 phases/tile; 12 ds_read_b128 pre-barrier + 32
// MFMA per phase; stage A@ph0/B@ph1; vmcnt(0)+barrier once per tile.
// XOR k-chunk swizzle (phys = kc ^ (row&7)), inverse applied on global src.
// f_out: 0 = bf16 C, 1 = fp32 C.
// ---------------------------------------------------------------------------
__device__ __forceinline__ void gemm256_core8(const short* __restrict__ A,
                                              const short* __restrict__ W,
                                              void* __restrict__ C,
                                              int f_out,
                                              long m0, int n0, short* lds) {
    constexpr int K = 1024, N = 1024;
    const int tid  = threadIdx.x;
    const int lane = tid & 63;
    const int wid  = tid >> 6;
    const int wm = wid >> 2, wn = wid & 3;

    short* A0 = lds;              // 16384 shorts = 32KB each
    short* B0 = lds + 16384;
    short* A1 = lds + 32768;
    short* B1 = lds + 49152;

    const int srl = tid >> 3;                    // 0..63
    const int kcs = (tid & 7) ^ (srl & 7);
    int aoff[4], boff[4];
    #pragma unroll
    for (int i = 0; i < 4; ++i) {
        const int row = i * 64 + srl;
        aoff[i] = (int)((m0 + row) * K + kcs * 8);
        boff[i] = (n0 + row) * K + kcs * 8;
    }
    const int ldsw = wid * 512;

    f32x4 acc[8][4] = {};

    #pragma unroll
    for (int i = 0; i < 4; ++i) gload_lds16(A + aoff[i], A0 + i * 4096 + ldsw);
    #pragma unroll
    for (int i = 0; i < 4; ++i) gload_lds16(W + boff[i], B0 + i * 4096 + ldsw);
    asm volatile("s_waitcnt vmcnt(0)" ::: "memory");
    __builtin_amdgcn_s_barrier();

    for (int t = 0; t < 16; ++t) {
        const int cur = t & 1;
        const short* rA = cur ? A1 : A0;
        const short* rB = cur ? B1 : B0;
        short* sA = cur ? A0 : A1;
        short* sB = cur ? B0 : B1;
        const int kadd = (t + 1) * 64;
        const bool more = (t < 15);

        #pragma unroll
        for (int ks = 0; ks < 2; ++ks) {
            const int kx8 = ((ks * 4 + (lane >> 4)) ^ (lane & 7)) * 8;
            bf16x8 af[8], bfr[4];
            #pragma unroll
            for (int m = 0; m < 8; ++m)
                af[m] = *(const bf16x8*)(rA + ((wm * 128 + m * 16 + (lane & 15)) * 64) + kx8);
            #pragma unroll
            for (int n = 0; n < 4; ++n)
                bfr[n] = *(const bf16x8*)(rB + ((wn * 64 + n * 16 + (lane & 15)) * 64) + kx8);
            __builtin_amdgcn_sched_barrier(0);
            __builtin_amdgcn_s_barrier();              // bar_a
            __builtin_amdgcn_sched_barrier(0);
            if (more) {
                if (ks == 0) {
                    #pragma unroll
                    for (int i = 0; i < 4; ++i)
                        gload_lds16(A + aoff[i] + kadd, sA + i * 4096 + ldsw);
                } else {
                    #pragma unroll
                    for (int i = 0; i < 4; ++i)
                        gload_lds16(W + boff[i] + kadd, sB + i * 4096 + ldsw);
                }
            }
            asm volatile("s_waitcnt lgkmcnt(0)" ::: "memory");
            __builtin_amdgcn_sched_barrier(0);
            __builtin_amdgcn_s_setprio(1);
            #pragma unroll
            for (int m = 0; m < 8; ++m)
                #pragma unroll
                for (int n = 0; n < 4; ++n)
                    acc[m][n] = __builtin_amdgcn_mfma_f32_16x16x32_bf16(
                                    af[m], bfr[n], acc[m][n], 0, 0, 0);
            __builtin_amdgcn_s_setprio(0);
            __builtin_amdgcn_sched_barrier(0);
            if (ks == 1) {
                asm volatile("s_waitcnt vmcnt(0)" ::: "memory");
                __builtin_amdgcn_s_barrier();          // bar_b
            }
        }
    }

    #pragma unroll
    for (int mf = 0; mf < 8; ++mf) {
        #pragma unroll
        for (int nf = 0; nf < 4; ++nf) {
            const int  col   = n0 + wn * 64 + nf * 16 + (lane & 15);
            const long rbase = m0 + wm * 128 + mf * 16 + (lane >> 4) * 4;
            if (f_out) {
                float* Cf = (float*)C;
                #pragma unroll
                for (int r = 0; r < 4; ++r)
                    Cf[(rbase + r) * N + col] = acc[mf][nf][r];
            } else {
                short* Cs = (short*)C;
                #pragma unroll
                for (int r = 0; r < 4; ++r)
                    Cs[(rbase + r) * N + col] = f2bf(acc[mf][nf][r]);
            }
        }
    }
}

// ---------------------------------------------------------------------------
// CORE-4 (out): 256 thr = 4 waves (2Mx2N), wave tile 128x128 (r13).
// ---------------------------------------------------------------------------
__device__ __forceinline__ void gemm256_core4(const short* __restrict__ A,
                                              const short* __restrict__ W,
                                              void* __restrict__ C,
                                              int f_out,
                                              long m0, int n0, short* lds) {
    constexpr int K = 1024, N = 1024;
    const int tid  = threadIdx.x;
    const int lane = tid & 63;
    const int wid  = tid >> 6;
    const int wm = wid >> 1, wn = wid & 1;

    short* A0 = lds;
    short* B0 = lds + 16384;
    short* A1 = lds + 32768;
    short* B1 = lds + 49152;

    const int srl = tid >> 3;                    // 0..31
    const int kcs = (tid & 7) ^ (srl & 7);
    int aoff[8], boff[8];
    #pragma unroll
    for (int i = 0; i < 8; ++i) {
        const int row = i * 32 + srl;
        aoff[i] = (int)((m0 + row) * K + kcs * 8);
        boff[i] = (n0 + row) * K + kcs * 8;
    }
    const int ldsw = wid * 512;

    f32x4 acc[8][8] = {};

    #pragma unroll
    for (int i = 0; i < 8; ++i) gload_lds16(A + aoff[i], A0 + i * 2048 + ldsw);
    #pragma unroll
    for (int i = 0; i < 8; ++i) gload_lds16(W + boff[i], B0 + i * 2048 + ldsw);
    asm volatile("s_waitcnt vmcnt(0)" ::: "memory");
    __builtin_amdgcn_s_barrier();

    const int arow = wm * 128 + (lane & 15);
    const int brow = wn * 128 + (lane & 15);

    for (int t = 0; t < 16; ++t) {
        const int cur = t & 1;
        const short* rA = cur ? A1 : A0;
        const short* rB = cur ? B1 : B0;
        short* sA = cur ? A0 : A1;
        short* sB = cur ? B0 : B1;
        const int kadd = (t + 1) * 64;
        const bool more = (t < 15);

        #pragma unroll
        for (int ks = 0; ks < 2; ++ks) {
            const int kx8 = ((ks * 4 + (lane >> 4)) ^ (lane & 7)) * 8;
            bf16x8 af[8], bfr[8];
            #pragma unroll
            for (int m = 0; m < 8; ++m)
                af[m] = *(const bf16x8*)(rA + ((arow + m * 16) * 64) + kx8);
            #pragma unroll
            for (int n = 0; n < 8; ++n)
                bfr[n] = *(const bf16x8*)(rB + ((brow + n * 16) * 64) + kx8);
            __builtin_amdgcn_sched_barrier(0);
            __builtin_amdgcn_s_barrier();
            __builtin_amdgcn_sched_barrier(0);
            if (more) {
                if (ks == 0) {
                    #pragma unroll
                    for (int i = 0; i < 8; ++i)
                        gload_lds16(A + aoff[i] + kadd, sA + i * 2048 + ldsw);
                } else {
                    #pragma unroll
                    for (int i = 0; i < 8; ++i)
                        gload_lds16(W + boff[i] + kadd, sB + i * 2048 + ldsw);
                }
            }
            asm volatile("s_waitcnt lgkmcnt(0)" ::: "memory");
            __builtin_amdgcn_sched_barrier(0);
            __builtin_amdgcn_s_setprio(1);
            #pragma unroll
            for (int m = 0; m < 8; ++m)
                #pragma unroll
                for (int n = 0; n < 8; ++n)
                    acc[m][n] = __builtin_amdgcn_mfma_f32_16x16x32_bf16(
                                    af[m], bfr[n], acc[m][n], 0, 0, 0);
            __builtin_amdgcn_s_setprio(0);
            __builtin_amdgcn_sched_barrier(0);
            if (ks == 1) {
                asm volatile("s_waitcnt vmcnt(0)" ::: "memory");
                __builtin_amdgcn_s_barrier();
            }
        }
    }

    #pragma unroll
    for (int mf = 0; mf < 8; ++mf) {
        #pragma unroll
        for (int nf = 0; nf < 8; ++nf) {
            const int  col   = n0 + wn * 128 + nf * 16 + (lane & 15);
            const long rbase = m0 + wm * 128 + mf * 16 + (lane >> 4) * 4;
            if (f_out) {
                float* Cf = (float*)C;
                #pragma unroll
                for (int r = 0; r < 4; ++r)
                    Cf[(rbase + r) * N + col] = acc[mf][nf][r];
            } else {
                short* Cs = (short*)C;
                #pragma unroll
                for (int r = 0; r < 4; ++r)
                    Cs[(rbase + r) * N + col] = f2bf(acc[mf][nf][r]);
            }
        }
    }
}

// QKV (core-8): nwg = (Mc/256)*12, XCD-bijective remap, A-panel grouped.
__global__ __launch_bounds__(512, 2) void gemm_qkv256(const short* __restrict__ A,
                                                      const short* __restrict__ W0,
                                                      const short* __restrict__ W1,
                                                      const short* __restrict__ W2,
                                                      short* __restrict__ C0,
                                                      short* __restrict__ C1,
                                                      short* __restrict__ C2) {
    __shared__ __align__(16) short lds[65536];            // 128 KiB
    const int nwg = gridDim.x;
    const int q8  = nwg >> 3;
    const int d   = blockIdx.x;
    const int lin = (d & 7) * q8 + (d >> 3);
    const int x   = lin / 12;
    const int r   = lin - x * 12;
    const int yy  = r / 3;
    const int z   = r - yy * 3;
    const short* W = (z == 0) ? W0 : (z == 1) ? W1 : W2;
    short*       C = (z == 0) ? C0 : (z == 1) ? C1 : C2;
    gemm256_core8(A, W, C, 0, (long)x * 256, yy * 256, lds);
}

// OUT (core-4): nwg = (Mc/256)*4. A pre-rebased by caller (A - moff*K).
// Output dtype sniffed inline from X (matches input dtype).
__global__ __launch_bounds__(256, 1) void gemm_out256(const short* __restrict__ A,
                                                      const short* __restrict__ W,
                                                      void* __restrict__ C,
                                                      long moff,
                                                      const unsigned* __restrict__ xs) {
    __shared__ __align__(16) short lds[65536];
    const int f = sniff_fp32(xs);
    const int nwg = gridDim.x;
    const int q8  = nwg >> 3;
    const int d   = blockIdx.x;
    const int lin = (d & 7) * q8 + (d >> 3);
    const int x   = lin >> 2;
    const int yy  = lin & 3;
    gemm256_core4(A, W, C, f, moff + (long)x * 256, yy * 256, lds);
}

// ---------------------------------------------------------------------------
// Per-token head mixing: scores = Q[16,64]@K[16,64]^T/8, softmax, Z = P@V.
// One wave per token, 4 tokens per 256-thread block.
// ---------------------------------------------------------------------------
__global__ __launch_bounds__(256) void attn_mix(const short* __restrict__ Q,
                                                const short* __restrict__ K,
                                                const short* __restrict__ V,
                                                short* __restrict__ Z) {
    constexpr int RS = 72;
    __shared__ short sq[4][16 * RS];
    __shared__ short sk[4][16 * RS];
    __shared__ short sv[4][16 * RS];
    __shared__ float sp[4][256];

    const int  tid  = threadIdx.x;
    const int  lane = tid & 63;
    const int  w    = tid >> 6;
    const long tok  = (long)blockIdx.x * 4 + w;

    const short* qg = Q + tok * 1024;
    const short* kg = K + tok * 1024;
    const short* vg = V + tok * 1024;

    #pragma unroll
    for (int it = 0; it < 2; ++it) {
        const int c   = lane + 64 * it;
        const int row = c >> 3;
        const int cc  = (c & 7) * 8;
        *(bf16x8*)&sq[w][row * RS + cc] = *(const bf16x8*)(qg + c * 8);
        *(bf16x8*)&sk[w][row * RS + cc] = *(const bf16x8*)(kg + c * 8);
        *(bf16x8*)&sv[w][row * RS + cc] = *(const bf16x8*)(vg + c * 8);
    }
    __syncthreads();

    const int h  = lane >> 2;
    const int t0 = (lane & 3) * 4;
    float sc[4] = {0.f, 0.f, 0.f, 0.f};
    for (int d = 0; d < 64; ++d) {
        const float qv = bf2f(sq[w][h * RS + d]);
        #pragma unroll
        for (int j = 0; j < 4; ++j)
            sc[j] += qv * bf2f(sk[w][(t0 + j) * RS + d]);
    }
    #pragma unroll
    for (int j = 0; j < 4; ++j) sc[j] *= 0.125f;

    float mx = fmaxf(fmaxf(sc[0], sc[1]), fmaxf(sc[2], sc[3]));
    mx = fmaxf(mx, __shfl_xor(mx, 1));
    mx = fmaxf(mx, __shfl_xor(mx, 2));
    float ex[4], s = 0.f;
    #pragma unroll
    for (int j = 0; j < 4; ++j) { ex[j] = __expf(sc[j] - mx); s += ex[j]; }
    s += __shfl_xor(s, 1);
    s += __shfl_xor(s, 2);
    const float inv = 1.f / s;
    #pragma unroll
    for (int j = 0; j < 4; ++j) sp[w][h * 16 + t0 + j] = ex[j] * inv;
    __syncthreads();

    const int dbase = (lane & 3) * 16;
    float o[16] = {};
    for (int t = 0; t < 16; ++t) {
        const float p = sp[w][h * 16 + t];
        const bf16x8 v0 = *(const bf16x8*)&sv[w][t * RS + dbase];
        const bf16x8 v1 = *(const bf16x8*)&sv[w][t * RS + dbase + 8];
        #pragma unroll
        for (int e = 0; e < 8; ++e) {
            o[e]     += p * bf2f(v0[e]);
            o[e + 8] += p * bf2f(v1[e]);
        }
    }
    bf16x8 ov0, ov1;
    #pragma unroll
    for (int e = 0; e < 8; ++e) { ov0[e] = f2bf(o[e]); ov1[e] = f2bf(o[e + 8]); }
    *(bf16x8*)(Z + tok * 1024 + lane * 16)     = ov0;
    *(bf16x8*)(Z + tok * 1024 + lane * 16 + 8) = ov1;
}

// ---------------------------------------------------------------------------
extern "C" void kernel_launch(void* const* d_in, const int* in_sizes, int n_in,
                              void* d_out, int out_size, void* d_ws, size_t ws_size,
                              hipStream_t stream) {
    const void* X = d_in[0];                   // [32768,1024] fp32 (detected)

    const long TOT = 32768;
    constexpr long WELEM = 1024 * 1024;

    char* ws   = (char*)d_ws;
    short* Wqb = (short*)(ws + 256);           // [Wq|Wk|Wv|Wo|Xb] contiguous
    short* Wkb = Wqb + WELEM;
    short* Wvb = Wkb + WELEM;
    short* Wob = Wvb + WELEM;
    short* dyn = Wob + WELEM;

    const size_t fixed = 256 + 4 * WELEM * 2;
    long chunk = 256;
    const long tiers[4] = {32768, 8192, 2048, 512};
    for (int i = 0; i < 4; ++i)
        if (fixed + (size_t)6 * tiers[i] * 1024 * 2 <= ws_size) { chunk = tiers[i]; break; }

    short* Xb = dyn;                 // chunk*1024 bf16 (contiguous after Wob)
    short* Qb = Xb + chunk * 1024;
    short* Kb = Qb + chunk * 1024;
    short* Vb = Kb + chunk * 1024;
    short* Zb = Vb + chunk * 1024;

    if (chunk == TOT) {
        convert_all<<<2048, 256, 0, stream>>>(X, d_in[1], d_in[2], d_in[3], d_in[4],
                                              Wqb, 4 * WELEM + TOT * 1024);
        gemm_qkv256<<<dim3((TOT / 256) * 12), 512, 0, stream>>>(Xb, Wqb, Wkb, Wvb,
                                                                Qb, Kb, Vb);
        attn_mix<<<dim3(TOT / 4), 256, 0, stream>>>(Qb, Kb, Vb, Zb);
        gemm_out256<<<dim3((TOT / 256) * 4), 256, 0, stream>>>(Zb, Wob, d_out, 0,
                                                               (const unsigned*)X);
    } else {
        convert_all<<<512, 256, 0, stream>>>(X, d_in[1], d_in[2], d_in[3], d_in[4],
                                             Wqb, 4 * WELEM);
        for (long t0 = 0; t0 < TOT; t0 += chunk) {
            convert_all<<<2048, 256, 0, stream>>>(
                (const void*)((const char*)X + (size_t)t0 * 1024 * 4),
                d_in[1], d_in[2], d_in[3], d_in[4],
                Xb - 4 * WELEM, 4 * WELEM + chunk * 1024);
            gemm_qkv256<<<dim3((chunk / 256) * 12), 512, 0, stream>>>(Xb, Wqb, Wkb, Wvb,
                                                                      Qb, Kb, Vb);
            attn_mix<<<dim3(chunk / 4), 256, 0, stream>>>(Qb, Kb, Vb, Zb);
            gemm_out256<<<dim3((chunk / 256) * 4), 256, 0, stream>>>(Zb - t0 * 1024, Wob,
                                                                     d_out, t0,
                                                                     (const unsigned*)X);
        }
    }
}